// Round 17
// baseline (353.878 us; speedup 1.0000x reference)
//
#include <hip/hip_runtime.h>
#include <hip/hip_bf16.h>

// THLSTM cell fused, MI355X gfx950 — round 17.
// K-split pairs: 16 waves/WG (BT=32), wave (cs,ks) = col-slice cs, K-half ks.
// Each pair reads each weight byte ONCE -> per-CU L2 B-traffic halves
// (the r9 plateau's binder per Little's-law accounting: 70 GB/s/CU ~ 52% of
// per-XCD L2 ceiling). Inner loop identical to r9 (1 acc, ring-2, arch<=64).
// Partials combined via LDS (bf16 partner half, ping-pong, 1 barrier/gate);
// each wave epilogues its 8 acc rows (cacc[8], ipk[4] - leaner than r9).

constexpr int Btot = 65536;
constexpr int H    = 256;
constexpr int I    = 128;
constexpr int K1   = 384;    // [h|x]
constexpr int BT   = 32;     // batch rows per WG
constexpr int NTHR = 1024;   // 16 waves
constexpr int SOFF = 24576;  // s-tile base: 48 k8 x 32 rows x 16B
constexpr int POFF = 40960;  // partial buffers: 2 x 32KB (ping-pong)

typedef __bf16 bf16x8  __attribute__((ext_vector_type(8)));
typedef float  f32x16  __attribute__((ext_vector_type(16)));
typedef float  f32x4v  __attribute__((ext_vector_type(4)));
typedef unsigned short ushort8 __attribute__((ext_vector_type(8)));

__device__ __forceinline__ unsigned short f2bf(float f) {
    unsigned u = __builtin_bit_cast(unsigned, f);
    u += 0x7fffu + ((u >> 16) & 1u);   // RNE
    return (unsigned short)(u >> 16);
}
__device__ __forceinline__ float bf2f(unsigned short s) {
    return __builtin_bit_cast(float, ((unsigned)s) << 16);
}
__device__ __forceinline__ float sigm(float x) {
    return __builtin_amdgcn_rcpf(1.0f + exp2f(-1.4426950408889634f * x));
}
__device__ __forceinline__ float tanh_f(float x) {
    return 1.0f - 2.0f * __builtin_amdgcn_rcpf(1.0f + exp2f(2.8853900817779268f * x));
}

// Weights bf16, layout [k8][col][8]: elem (col, k=k8*8+e) at (k8*256+col)*8+e.
// w0: 48 k8 (K=384); per gate wg: 80 k8 (K=640: h|x|s), gates f,i,T,u,o.
__global__ void convert_w(const float* __restrict__ Wh, const float* __restrict__ Wx,
                          const float* __restrict__ Ws, unsigned short* __restrict__ w0,
                          unsigned short* __restrict__ wg) {
    const int t  = blockIdx.x * blockDim.x + threadIdx.x;
    const int N0 = 48 * 2048;        // 98304
    const int N1 = 5 * 80 * 2048;    // 819200
    if (t < N0) {
        const int k8 = t >> 11, rem = t & 2047;
        const int col = rem >> 3, e = rem & 7;
        const int k = k8 * 8 + e;
        const float v = (k < H) ? Wh[col * H + k] : Wx[col * I + (k - H)];
        w0[t] = f2bf(v);
    } else if (t < N0 + N1) {
        const int u   = t - N0;
        const int g1  = u / 163840;
        const int rem = u - g1 * 163840;
        const int k8  = rem >> 11;
        const int r2  = rem & 2047;
        const int col = r2 >> 3, e = r2 & 7;
        const int k   = k8 * 8 + e;
        const int g   = g1 + 1;
        float v;
        if (k < H)        v = Wh[g * H * H + col * H + k];
        else if (k < K1)  v = Wx[g * H * I + col * I + (k - H)];
        else              v = Ws[g1 * H * H + col * H + (k - K1)];
        wg[u] = f2bf(v);
    }
}

// K-loop: 1 A stream, 1 B stream, single acc chain. Ring depth 2. (r9's loop)
template<int NIT>
__device__ __forceinline__ void gemm1(const unsigned char* Ab, int abase,
        const unsigned short* __restrict__ Wp, f32x16& acc) {
    bf16x8 b[2], a[2];
    #pragma unroll
    for (int i = 0; i < 2; ++i) {
        b[i] = *(const bf16x8*)(Wp + i * 4096);
        a[i] = *(const bf16x8*)(Ab + abase + i * 1024);
    }
    #pragma unroll
    for (int i = 0; i < NIT; ++i) {
        const bf16x8 av = a[i & 1], bv = b[i & 1];
        if (i + 2 < NIT) {
            a[i & 1] = *(const bf16x8*)(Ab + abase + (i + 2) * 1024);
            b[i & 1] = *(const bf16x8*)(Wp + (i + 2) * 4096);
        }
        acc = __builtin_amdgcn_mfma_f32_32x32x16_bf16(av, bv, acc, 0, 0, 0);
    }
}

// Pair-combine through LDS: write own 16 partials (bf16, conflict-free
// lane*16 layout), barrier, read partner's half for this wave's 8 rows.
__device__ __forceinline__ void combine(unsigned char* Ab, const f32x16& acc,
        int pw0, int pw1, int prd, int ks, int pp, float full[8]) {
    ushort8 p0, p1;
    #pragma unroll
    for (int j = 0; j < 8; ++j) { p0[j] = f2bf(acc[j]); p1[j] = f2bf(acc[8 + j]); }
    *(ushort8*)(Ab + pp * 32768 + pw0) = p0;
    *(ushort8*)(Ab + pp * 32768 + pw1) = p1;
    __syncthreads();
    const ushort8 q = *(const ushort8*)(Ab + pp * 32768 + prd);
    #pragma unroll
    for (int j = 0; j < 8; ++j) full[j] = acc[ks * 8 + j] + bf2f(q[j]);
}

__global__ __launch_bounds__(NTHR, 4) void thlstm_fused(
        const float* __restrict__ x_t, const float* __restrict__ delta_t,
        const float* __restrict__ h_prev, const float* __restrict__ c_prev,
        const float* __restrict__ Wst, const float* __restrict__ bias,
        const unsigned short* __restrict__ w0, const unsigned short* __restrict__ wg,
        float* __restrict__ out) {
    __shared__ __align__(16) unsigned char Abuf[106496];  // 40KB A/s + 64KB partials
    const int tid = threadIdx.x;
    const int b0  = blockIdx.x * BT;

    // ---- stage h|x bf16 (nt loads): chunk (k8, row) at (k8*32+row)*16 ----
    #pragma unroll
    for (int it = 0; it < 2; ++it) {
        const int c = it * NTHR + tid;
        if (c < BT * 48) {
            const int k8 = c >> 5, row = c & 31;
            const float* src = (k8 < 32) ? (h_prev + (size_t)(b0 + row) * H + k8 * 8)
                                         : (x_t    + (size_t)(b0 + row) * I + (k8 - 32) * 8);
            const f32x4v v0 = __builtin_nontemporal_load((const f32x4v*)src);
            const f32x4v v1 = __builtin_nontemporal_load(((const f32x4v*)src) + 1);
            ushort8 p;
            p[0] = f2bf(v0[0]); p[1] = f2bf(v0[1]); p[2] = f2bf(v0[2]); p[3] = f2bf(v0[3]);
            p[4] = f2bf(v1[0]); p[5] = f2bf(v1[1]); p[6] = f2bf(v1[2]); p[7] = f2bf(v1[3]);
            *(ushort8*)(Abuf + (k8 * 32 + row) * 16) = p;
        }
    }
    __syncthreads();

    const int lane  = tid & 63;
    const int wv    = tid >> 6;           // 0..15
    const int cs    = wv >> 1;            // col-slice 0..7 -> cols cs*32..+31
    const int ks    = wv & 1;             // K-half
    const int half  = lane >> 5;
    const int l31   = lane & 31;
    const int ocol  = cs * 32 + l31;
    const int rbase = 4 * half;
    const int abase = half * 512 + l31 * 16;
    const int wlo   = half * 2048 + ocol * 8;                      // shorts
    const int sbase = SOFF + (ocol >> 3) * 512 + (ocol & 7) * 2;
    // partial slots (conflict-free: lane*16 contiguous)
    const int pw0 = POFF + wv * 1024 + lane * 16;            // own r0..7
    const int pw1 = POFF + 16384 + wv * 1024 + lane * 16;    // own r8..15
    const int prd = POFF + ks * 16384 + (wv ^ 1) * 1024 + lane * 16;  // partner, my half

    // ---- gate s: K=384, split 12+12 ----
    {
        f32x16 acc;
        #pragma unroll
        for (int r = 0; r < 16; ++r) acc[r] = 0.f;
        gemm1<12>(Abuf, abase + ks * 12 * 1024, w0 + wlo + ks * 12 * 4096, acc);
        float full[8];
        combine(Abuf, acc, pw0, pw1, prd, ks, 0, full);
        const float wst = Wst[ocol];
        const float bs  = bias[ocol];
        #pragma unroll
        for (int j = 0; j < 8; ++j) {
            const int r = ks * 8 + j;
            const int mrow = (r & 3) + 8 * (r >> 2) + rbase;
            const float sv = tanh_f(full[j] + delta_t[b0 + mrow] * wst + bs);
            *(unsigned short*)(Abuf + sbase + mrow * 16) = f2bf(sv);
        }
    }
    __syncthreads();   // s-tile visible to all A-streams

    float    cacc[8];
    unsigned ipk[4];

    // ---- gate f (wg 0, bias 1): c = f * c_prev ----
    {
        f32x16 acc;
        #pragma unroll
        for (int r = 0; r < 16; ++r) acc[r] = 0.f;
        gemm1<20>(Abuf, abase + ks * 20 * 1024, wg + 0 * 163840 + wlo + ks * 20 * 4096, acc);
        float full[8];
        combine(Abuf, acc, pw0, pw1, prd, ks, 1, full);
        const float bg = bias[1 * H + ocol];
        #pragma unroll
        for (int j = 0; j < 8; ++j) {
            const int r = ks * 8 + j;
            const int mrow = (r & 3) + 8 * (r >> 2) + rbase;
            const size_t idx = (size_t)(b0 + mrow) * H + ocol;
            cacc[j] = sigm(full[j] + bg) * __builtin_nontemporal_load(&c_prev[idx]);
        }
    }
    // ---- gate T (wg 2, bias 3): c += T * s ----
    {
        f32x16 acc;
        #pragma unroll
        for (int r = 0; r < 16; ++r) acc[r] = 0.f;
        gemm1<20>(Abuf, abase + ks * 20 * 1024, wg + 2 * 163840 + wlo + ks * 20 * 4096, acc);
        float full[8];
        combine(Abuf, acc, pw0, pw1, prd, ks, 0, full);
        const float bg = bias[3 * H + ocol];
        #pragma unroll
        for (int j = 0; j < 8; ++j) {
            const int r = ks * 8 + j;
            const int mrow = (r & 3) + 8 * (r >> 2) + rbase;
            const float sv = bf2f(*(const unsigned short*)(Abuf + sbase + mrow * 16));
            cacc[j] += sigm(full[j] + bg) * sv;
        }
    }
    // ---- gate i (wg 1, bias 2): keep packed ----
    {
        f32x16 acc;
        #pragma unroll
        for (int r = 0; r < 16; ++r) acc[r] = 0.f;
        gemm1<20>(Abuf, abase + ks * 20 * 1024, wg + 1 * 163840 + wlo + ks * 20 * 4096, acc);
        float full[8];
        combine(Abuf, acc, pw0, pw1, prd, ks, 1, full);
        const float bg = bias[2 * H + ocol];
        float tmpf = 0.f;
        #pragma unroll
        for (int j = 0; j < 8; ++j) {
            const float sg = sigm(full[j] + bg);
            if ((j & 1) == 0) tmpf = sg;
            else ipk[j >> 1] = (unsigned)f2bf(tmpf) | ((unsigned)f2bf(sg) << 16);
        }
    }
    // ---- gate u (wg 3, bias 4): c += i * tanh(u) ----
    {
        f32x16 acc;
        #pragma unroll
        for (int r = 0; r < 16; ++r) acc[r] = 0.f;
        gemm1<20>(Abuf, abase + ks * 20 * 1024, wg + 3 * 163840 + wlo + ks * 20 * 4096, acc);
        float full[8];
        combine(Abuf, acc, pw0, pw1, prd, ks, 0, full);
        const float bg = bias[4 * H + ocol];
        #pragma unroll
        for (int j = 0; j < 8; ++j) {
            const float iv = bf2f((unsigned short)((ipk[j >> 1] >> ((j & 1) * 16)) & 0xffffu));
            cacc[j] += iv * tanh_f(full[j] + bg);
        }
    }
    // ---- gate o (wg 4, bias 5): outputs (nt stores) ----
    {
        f32x16 acc;
        #pragma unroll
        for (int r = 0; r < 16; ++r) acc[r] = 0.f;
        gemm1<20>(Abuf, abase + ks * 20 * 1024, wg + 4 * 163840 + wlo + ks * 20 * 4096, acc);
        float full[8];
        combine(Abuf, acc, pw0, pw1, prd, ks, 1, full);
        const float bg = bias[5 * H + ocol];
        #pragma unroll
        for (int j = 0; j < 8; ++j) {
            const int r = ks * 8 + j;
            const int mrow = (r & 3) + 8 * (r >> 2) + rbase;
            const size_t idx = (size_t)(b0 + mrow) * H + ocol;
            const float c = cacc[j];
            __builtin_nontemporal_store(sigm(full[j] + bg) * tanh_f(c), &out[idx]);
            __builtin_nontemporal_store(c, &out[(size_t)Btot * H + idx]);
        }
    }
}

extern "C" void kernel_launch(void* const* d_in, const int* in_sizes, int n_in,
                              void* d_out, int out_size, void* d_ws, size_t ws_size,
                              hipStream_t stream) {
    (void)in_sizes; (void)n_in; (void)out_size; (void)ws_size;
    const float* x_t    = (const float*)d_in[0];
    const float* delta  = (const float*)d_in[1];
    const float* h_prev = (const float*)d_in[2];
    const float* c_prev = (const float*)d_in[3];
    const float* Wh     = (const float*)d_in[4];
    const float* Wx     = (const float*)d_in[5];
    const float* Ws     = (const float*)d_in[6];
    const float* Wst    = (const float*)d_in[7];
    const float* bias   = (const float*)d_in[8];
    float* out = (float*)d_out;

    unsigned short* w0 = (unsigned short*)d_ws;   // 48*2048 bf16
    unsigned short* wg = w0 + 48 * 2048;          // 5*80*2048 bf16

    const int total = 48 * 2048 + 5 * 80 * 2048;  // 917504
    convert_w<<<(total + 255) / 256, 256, 0, stream>>>(Wh, Wx, Ws, w0, wg);
    thlstm_fused<<<Btot / BT, NTHR, 0, stream>>>(x_t, delta, h_prev, c_prev,
                                                 Wst, bias, w0, wg, out);
}